// Round 1
// baseline (15347.232 us; speedup 1.0000x reference)
//
#include <hip/hip_runtime.h>

typedef __bf16 bf16x8 __attribute__((ext_vector_type(8)));
typedef float  f32x4  __attribute__((ext_vector_type(4)));
typedef unsigned short u16;
typedef unsigned int   u32;

#define SEQ   512
#define BATCH 64
#define INP   1024
#define HID   1024
#define NBLK  64

// ---- workspace layout (bytes) ----
// xb   : 512*64*1024 u16      = 67108864
// wc   : 4096*2048  u16       = 16777216   ([W_ih | W_hh], row n k-contiguous)
// hb   : 2*64*1024  u16       = 262144     (h double buffer, bf16)
// bias : 4096 f32             = 16384      (b_ih + b_hh)
// cnt  : 1 u32
#define XB_OFF   0ull
#define WC_OFF   (XB_OFF + 67108864ull)
#define HB_OFF   (WC_OFF + 16777216ull)
#define BIAS_OFF (HB_OFF + 262144ull)
#define CNT_OFF  (BIAS_OFF + 16384ull)

__device__ __forceinline__ u16 f2bf(float f) {
    u32 u = __float_as_uint(f);
    u = (u + 0x7FFFu + ((u >> 16) & 1u)) >> 16;
    return (u16)u;
}

__device__ __forceinline__ bf16x8 ld8(const u16* p) {
    return *reinterpret_cast<const bf16x8*>(p);
}

__device__ __forceinline__ float sigmoidf_fast(float x) {
    return 1.0f / (1.0f + __expf(-x));
}
__device__ __forceinline__ float tanhf_fast(float x) {
    // tanh(x) = 2*sigmoid(2x) - 1
    return 2.0f / (1.0f + __expf(-2.0f * x)) - 1.0f;
}

// ---------------- prep: fp32 -> bf16 conversion + init ----------------
__global__ void lstm_prep(const float* __restrict__ x,
                          const float* __restrict__ wih,
                          const float* __restrict__ whh,
                          const float* __restrict__ bih,
                          const float* __restrict__ bhh,
                          u16* __restrict__ xb, u16* __restrict__ wc,
                          u16* __restrict__ hb, float* __restrict__ bias,
                          u32* __restrict__ cnt) {
    const long long NX = 33554432ll;   // x elements
    const long long NW = 8388608ll;    // wc elements (4096*2048)
    const long long NB = 4096ll;
    const long long NH = 131072ll;     // both h buffers
    const long long total = NX + NW + NB + NH + 1;
    long long stride = (long long)gridDim.x * blockDim.x;
    for (long long i = (long long)blockIdx.x * blockDim.x + threadIdx.x;
         i < total; i += stride) {
        if (i < NX) {
            xb[i] = f2bf(x[i]);
        } else if (i < NX + NW) {
            long long j = i - NX;
            long long row = j >> 11;          // /2048
            long long col = j & 2047;
            float v = (col < 1024) ? wih[row * 1024 + col]
                                   : whh[row * 1024 + (col - 1024)];
            wc[j] = f2bf(v);
        } else if (i < NX + NW + NB) {
            long long j = i - NX - NW;
            bias[j] = bih[j] + bhh[j];
        } else if (i < NX + NW + NB + NH) {
            hb[i - NX - NW - NB] = 0;
        } else {
            cnt[0] = 0;
        }
    }
}

// ---------------- persistent recurrence ----------------
// 64 blocks x 256 threads. Block c owns h-cols [16c, 16c+16).
// Wave w (0..3) handles K-range [512w, 512w+512) of fused K=2048 ([x_t | h]).
// Partials for all 4 gates x 64 batch x 16 cols reduced via LDS.
__global__ __launch_bounds__(256, 1) void lstm_rec(
    const u16* __restrict__ xb, const u16* __restrict__ wc,
    const float* __restrict__ bias, const float* __restrict__ km,
    u16* __restrict__ hb, float* __restrict__ out,
    u32* __restrict__ cnt, const int* __restrict__ trainp) {

    __shared__ float part[4][4][BATCH][16];  // [wave][gate][b][j] = 64 KB

    const int tid  = threadIdx.x;
    const int w    = tid >> 6;
    const int lane = tid & 63;
    const int quad = lane >> 4;
    const int l16  = lane & 15;
    const int cu   = blockIdx.x;       // 0..63
    const int col0 = cu * 16;

    const int training = trainp[0];
    const float scale = training ? (1.0f / 0.9f) : 1.0f;

    // B (weights): row n = g*1024 + col0 + l16, k = w*512 + kk*32 + quad*8
    const u16* wbase = wc + (size_t)(col0 + l16) * 2048 + (size_t)w * 512
                          + (size_t)quad * 8;

    const int aIsX = (w < 2);
    const size_t aOffK = (size_t)(aIsX ? w : (w - 2)) * 512 + (size_t)quad * 8;

    // cell-update mapping: thread handles (b = (tid>>4) + 16r, j = tid&15)
    const int cj  = tid & 15;
    const int cb0 = tid >> 4;
    float bi0 = bias[0 * 1024 + col0 + cj];
    float bi1 = bias[1 * 1024 + col0 + cj];
    float bi2 = bias[2 * 1024 + col0 + cj];
    float bi3 = bias[3 * 1024 + col0 + cj];

    float creg[4] = {0.f, 0.f, 0.f, 0.f};   // c state, register-resident

    #pragma unroll 1
    for (int t = 0; t < SEQ; ++t) {
        const u16* Ab = aIsX
            ? (xb + (size_t)t * (BATCH * INP) + aOffK)
            : (hb + (size_t)(t & 1) * (BATCH * HID) + aOffK);
        const u16* Arow = Ab + (size_t)l16 * 1024;

        f32x4 acc[4][4];   // [gate][mtile]
        #pragma unroll
        for (int g = 0; g < 4; ++g)
            #pragma unroll
            for (int mt = 0; mt < 4; ++mt)
                acc[g][mt] = (f32x4){0.f, 0.f, 0.f, 0.f};

        #pragma unroll 4
        for (int kk = 0; kk < 16; ++kk) {
            bf16x8 afr[4], bfr[4];
            #pragma unroll
            for (int mt = 0; mt < 4; ++mt)
                afr[mt] = ld8(Arow + (size_t)mt * 16 * 1024 + kk * 32);
            #pragma unroll
            for (int g = 0; g < 4; ++g)
                bfr[g] = ld8(wbase + (size_t)g * 1024 * 2048 + kk * 32);
            #pragma unroll
            for (int g = 0; g < 4; ++g)
                #pragma unroll
                for (int mt = 0; mt < 4; ++mt)
                    acc[g][mt] = __builtin_amdgcn_mfma_f32_16x16x32_bf16(
                        afr[mt], bfr[g], acc[g][mt], 0, 0, 0);
        }

        // C layout: col = lane&15, row = quad*4 + reg  (per M-tile)
        #pragma unroll
        for (int g = 0; g < 4; ++g)
            #pragma unroll
            for (int mt = 0; mt < 4; ++mt)
                #pragma unroll
                for (int r = 0; r < 4; ++r)
                    part[w][g][mt * 16 + quad * 4 + r][l16] = acc[g][mt][r];

        __syncthreads();

        u16* hout = hb + (size_t)((t + 1) & 1) * (BATCH * HID);
        #pragma unroll
        for (int r = 0; r < 4; ++r) {
            int b = cb0 + 16 * r;
            float gi = part[0][0][b][cj] + part[1][0][b][cj]
                     + part[2][0][b][cj] + part[3][0][b][cj] + bi0;
            float gf = part[0][1][b][cj] + part[1][1][b][cj]
                     + part[2][1][b][cj] + part[3][1][b][cj] + bi1;
            float gg = part[0][2][b][cj] + part[1][2][b][cj]
                     + part[2][2][b][cj] + part[3][2][b][cj] + bi2;
            float go = part[0][3][b][cj] + part[1][3][b][cj]
                     + part[2][3][b][cj] + part[3][3][b][cj] + bi3;

            float ig = sigmoidf_fast(gi);
            float fg = sigmoidf_fast(gf);
            float gt = tanhf_fast(gg);
            float og = sigmoidf_fast(go);

            float cv = fg * creg[r] + ig * gt;
            creg[r] = cv;
            float hv = og * tanhf_fast(cv);
            int cidx = b * 1024 + col0 + cj;
            float m = km[(size_t)t * (BATCH * HID) + cidx];
            if (training) hv = hv * m * scale;
            hout[cidx] = f2bf(hv);
            if (t == SEQ - 1) out[cidx] = hv;
        }

        // ---- grid barrier (release/acquire, monotonic counter) ----
        __threadfence();      // flush my h stores to device scope
        __syncthreads();      // all threads' fences done; LDS reads done
        if (tid == 0) {
            __hip_atomic_fetch_add(cnt, 1u, __ATOMIC_ACQ_REL,
                                   __HIP_MEMORY_SCOPE_AGENT);
            u32 target = (u32)(t + 1) * NBLK;
            while (__hip_atomic_load(cnt, __ATOMIC_ACQUIRE,
                                     __HIP_MEMORY_SCOPE_AGENT) < target) {
                __builtin_amdgcn_s_sleep(1);
            }
        }
        __syncthreads();
        __threadfence();      // invalidate caches before reading new h
    }
}

extern "C" void kernel_launch(void* const* d_in, const int* in_sizes, int n_in,
                              void* d_out, int out_size, void* d_ws, size_t ws_size,
                              hipStream_t stream) {
    const float* x   = (const float*)d_in[0];
    const float* km  = (const float*)d_in[1];
    const float* wih = (const float*)d_in[2];
    const float* whh = (const float*)d_in[3];
    const float* bih = (const float*)d_in[4];
    const float* bhh = (const float*)d_in[5];
    const int*   tr  = (const int*)d_in[6];
    float* out = (float*)d_out;

    char* ws = (char*)d_ws;
    u16*   xb   = (u16*)(ws + XB_OFF);
    u16*   wc   = (u16*)(ws + WC_OFF);
    u16*   hb   = (u16*)(ws + HB_OFF);
    float* bias = (float*)(ws + BIAS_OFF);
    u32*   cnt  = (u32*)(ws + CNT_OFF);

    lstm_prep<<<dim3(2048), dim3(256), 0, stream>>>(x, wih, whh, bih, bhh,
                                                    xb, wc, hb, bias, cnt);
    lstm_rec<<<dim3(NBLK), dim3(256), 0, stream>>>(xb, wc, bias, km, hb,
                                                   out, cnt, tr);
}